// Round 7
// baseline (700.865 us; speedup 1.0000x reference)
//
#include <hip/hip_runtime.h>
#include <hip/hip_bf16.h>

#define HDIM 256
#define IDIM 512
#define NST 16
#define KCONV 4
#define LAYERS 4
#define BATCH 4
#define LSEQ 1024
#define TOK (BATCH * LSEQ)   // 4096

typedef unsigned short u16;
typedef float f32x4 __attribute__((ext_vector_type(4)));
typedef short bf16x8 __attribute__((ext_vector_type(8)));

static __device__ __forceinline__ u16 f2bf(float f) {
    __hip_bfloat16 h = __float2bfloat16(f);
    return reinterpret_cast<u16&>(h);
}
static __device__ __forceinline__ float bf2f(u16 b) {
    return __builtin_bit_cast(float, (unsigned)b << 16);
}
// unpack bf16 #j (j=0..3) from a uint2 holding 4 packed bf16
static __device__ __forceinline__ float bfup(uint2 u, int j) {
    unsigned w = (j < 2) ? u.x : u.y;
    unsigned bits = (j & 1) ? (w & 0xffff0000u) : (w << 16);
    return __builtin_bit_cast(float, bits);
}

// DPP butterfly add over each 16-lane row (all lanes end with the row sum).
#define DPP_ROW_ADD(p, CTRL)                                                   \
    p += __builtin_bit_cast(float, __builtin_amdgcn_update_dpp(                \
             0, __builtin_bit_cast(int, p), CTRL, 0xf, 0xf, false))

// -------------------- embedding --------------------
__global__ __launch_bounds__(256) void embed_kernel(const int* __restrict__ ids,
                                                    const float* __restrict__ embed,
                                                    float* __restrict__ h) {
    int idx = blockIdx.x * 256 + threadIdx.x;
    if (idx < TOK * HDIM) {
        int tok = idx >> 8;
        int c = idx & (HDIM - 1);
        h[idx] = embed[ids[tok] * HDIM + c];
    }
}

// -------------------- f32 -> bf16 bulk convert (weights) --------------------
__global__ __launch_bounds__(256) void cvt_bf16_kernel(const float* __restrict__ in,
                                                       u16* __restrict__ out, int n) {
    int j = (blockIdx.x * 256 + threadIdx.x) * 4;
    if (j < n) {
        float4 v = *(const float4*)&in[j];
        unsigned lo = (unsigned)f2bf(v.x) | ((unsigned)f2bf(v.y) << 16);
        unsigned hi = (unsigned)f2bf(v.z) | ((unsigned)f2bf(v.w) << 16);
        *(uint2*)&out[j] = make_uint2(lo, hi);
    }
}

// -------------------- rmsnorm (per token row of H=256), bf16 out --------------------
__global__ __launch_bounds__(256) void rmsnorm_kernel(const float* __restrict__ h,
                                                      const float* __restrict__ w,
                                                      u16* __restrict__ xb) {
    int tok = blockIdx.x;
    int c = threadIdx.x;
    float v = h[tok * HDIM + c];
    float s = v * v;
    #pragma unroll
    for (int m = 32; m >= 1; m >>= 1) s += __shfl_xor(s, m, 64);
    __shared__ float ls[4];
    __shared__ float rstd_s;
    int wid = threadIdx.x >> 6;
    if ((threadIdx.x & 63) == 0) ls[wid] = s;
    __syncthreads();
    if (threadIdx.x == 0) {
        float tot = ls[0] + ls[1] + ls[2] + ls[3];
        rstd_s = rsqrtf(tot * (1.0f / HDIM) + 1e-5f);
    }
    __syncthreads();
    xb[tok * HDIM + c] = f2bf(v * rstd_s * w[c]);
}

// -------------------- bf16 MFMA GEMM: C[M,N] = A[M,K](bf16) @ W[N,K](bf16)^T ----
// EPI: 1 = accumulate f32 (residual), 2 = store bf16.
template <int EPI>
__global__ __launch_bounds__(256) void gemm_bf16_kernel(const u16* __restrict__ A,
                                                        const u16* __restrict__ W,
                                                        float* __restrict__ C,
                                                        int M, int N, int K) {
    const int BM = 128, BK = 32;
    __shared__ __align__(16) u16 Al[BM][BK + 8];
    __shared__ __align__(16) u16 Bl[BM][BK + 8];
    int m0 = blockIdx.y * BM, n0 = blockIdx.x * BM;
    int tid = threadIdx.x;
    int lane = tid & 63;
    int wid = tid >> 6;
    int wr = wid >> 1, wc = wid & 1;
    int r = lane & 15, g = lane >> 4;

    f32x4 acc[4][4] = {};

    int srow = tid & 127;
    const u16* src = (tid < 128) ? (A + (size_t)(m0 + srow) * K)
                                 : (W + (size_t)(n0 + srow) * K);
    u16* dstrow = (tid < 128) ? &Al[srow][0] : &Bl[srow][0];

    for (int k0 = 0; k0 < K; k0 += BK) {
        uint4 v0 = *(const uint4*)(src + k0);
        uint4 v1 = *(const uint4*)(src + k0 + 8);
        uint4 v2 = *(const uint4*)(src + k0 + 16);
        uint4 v3 = *(const uint4*)(src + k0 + 24);
        __syncthreads();
        *(uint4*)(dstrow)      = v0;
        *(uint4*)(dstrow + 8)  = v1;
        *(uint4*)(dstrow + 16) = v2;
        *(uint4*)(dstrow + 24) = v3;
        __syncthreads();

        bf16x8 af[4], bfr[4];
        #pragma unroll
        for (int f = 0; f < 4; ++f) {
            af[f]  = *(const bf16x8*)&Al[wr * 64 + f * 16 + r][g * 8];
            bfr[f] = *(const bf16x8*)&Bl[wc * 64 + f * 16 + r][g * 8];
        }
        #pragma unroll
        for (int fm = 0; fm < 4; ++fm)
            #pragma unroll
            for (int fn = 0; fn < 4; ++fn)
                acc[fm][fn] = __builtin_amdgcn_mfma_f32_16x16x32_bf16(
                    af[fm], bfr[fn], acc[fm][fn], 0, 0, 0);
    }

    #pragma unroll
    for (int fm = 0; fm < 4; ++fm) {
        #pragma unroll
        for (int fn = 0; fn < 4; ++fn) {
            int col = n0 + wc * 64 + fn * 16 + r;
            #pragma unroll
            for (int v = 0; v < 4; ++v) {
                int row = m0 + wr * 64 + fm * 16 + g * 4 + v;
                if (EPI == 1) C[(size_t)row * N + col] += acc[fm][fn][v];
                else          ((u16*)C)[(size_t)row * N + col] = f2bf(acc[fm][fn][v]);
            }
        }
    }
}

// -------------------- x_proj fused: ssm-tile -> dtr + B_T/C_T --------------------
// One block = 64 tokens. bf16 MFMA over K=512: out[64][48], then epilogue writes
// dtr[tok][16] (f32), Bt/Ct[(b*16+n)*1024 + t] (f32, channel-major streams).
__global__ __launch_bounds__(256) void xproj_kernel(const u16* __restrict__ A,   // xsb [TOK][512]
                                                    const u16* __restrict__ W,   // xwb [48][512]
                                                    float* __restrict__ dtr,
                                                    float* __restrict__ Bt,
                                                    float* __restrict__ Ct) {
    const int BK = 32;
    __shared__ __align__(16) u16 Al[64][BK + 8];
    __shared__ __align__(16) u16 Bl[48][BK + 8];
    __shared__ float sT[64][52];
    int m0 = blockIdx.x * 64;
    int tid = threadIdx.x;
    int lane = tid & 63;
    int wid = tid >> 6;
    int r = lane & 15, g = lane >> 4;

    f32x4 acc[3] = {};

    const u16* src = nullptr;
    u16* dstrow = nullptr;
    if (tid < 64)       { src = A + (size_t)(m0 + tid) * 512; dstrow = &Al[tid][0]; }
    else if (tid < 112) { src = W + (size_t)(tid - 64) * 512; dstrow = &Bl[tid - 64][0]; }

    for (int k0 = 0; k0 < 512; k0 += BK) {
        uint4 v0, v1, v2, v3;
        if (tid < 112) {
            v0 = *(const uint4*)(src + k0);
            v1 = *(const uint4*)(src + k0 + 8);
            v2 = *(const uint4*)(src + k0 + 16);
            v3 = *(const uint4*)(src + k0 + 24);
        }
        __syncthreads();
        if (tid < 112) {
            *(uint4*)(dstrow)      = v0;
            *(uint4*)(dstrow + 8)  = v1;
            *(uint4*)(dstrow + 16) = v2;
            *(uint4*)(dstrow + 24) = v3;
        }
        __syncthreads();

        bf16x8 af = *(const bf16x8*)&Al[wid * 16 + r][g * 8];
        #pragma unroll
        for (int fn = 0; fn < 3; ++fn) {
            bf16x8 bfr = *(const bf16x8*)&Bl[fn * 16 + r][g * 8];
            acc[fn] = __builtin_amdgcn_mfma_f32_16x16x32_bf16(af, bfr, acc[fn], 0, 0, 0);
        }
    }

    #pragma unroll
    for (int fn = 0; fn < 3; ++fn) {
        int col = fn * 16 + r;
        #pragma unroll
        for (int v = 0; v < 4; ++v)
            sT[wid * 16 + g * 4 + v][col] = acc[fn][v];
    }
    __syncthreads();

    int b  = m0 >> 10;
    int tl = m0 & 1023;
    if (tid < 64) {
        float4* dst = (float4*)&dtr[(size_t)(m0 + tid) * 16];
        const float4* s4 = (const float4*)&sT[tid][0];
        dst[0] = s4[0]; dst[1] = s4[1]; dst[2] = s4[2]; dst[3] = s4[3];
    }
    #pragma unroll
    for (int k = 0; k < 4; ++k) {
        int idx = tid + k * 256;        // 0..1023 = 16n x 64t
        int n = idx >> 6, t = idx & 63;
        size_t off = (size_t)(b * 16 + n) * LSEQ + tl + t;
        Bt[off] = sT[t][16 + n];
        Ct[off] = sT[t][32 + n];
    }
}

// -------------------- generic f32 tiled GEMM (dt projection) --------------------
// C[M,N] = A[M,K(lda)] @ W[N,K(ldw)]^T; EPI 3 = softplus(acc + bias[row])
template <int EPI>
__global__ __launch_bounds__(256) void gemm_kernel(const float* __restrict__ A,
                                                   const float* __restrict__ W,
                                                   const float* __restrict__ bias,
                                                   float* __restrict__ C,
                                                   int M, int N, int K, int lda, int ldw) {
    const int BM = 64, BN = 64, BK = 16;
    __shared__ float As[BK][BM];
    __shared__ float Ws[BK][BN];
    int m0 = blockIdx.y * BM, n0 = blockIdx.x * BN;
    int tid = threadIdx.x;
    int tx = tid & 15, ty = tid >> 4;
    int lm = tid >> 2, lk = (tid & 3) * 4;

    float acc[4][4] = {};

    for (int k0 = 0; k0 < K; k0 += BK) {
        float4 a4 = *(const float4*)&A[(size_t)(m0 + lm) * lda + k0 + lk];
        As[lk + 0][lm] = a4.x; As[lk + 1][lm] = a4.y;
        As[lk + 2][lm] = a4.z; As[lk + 3][lm] = a4.w;
        float4 w4 = *(const float4*)&W[(size_t)(n0 + lm) * ldw + k0 + lk];
        Ws[lk + 0][lm] = w4.x; Ws[lk + 1][lm] = w4.y;
        Ws[lk + 2][lm] = w4.z; Ws[lk + 3][lm] = w4.w;
        __syncthreads();
        #pragma unroll
        for (int k = 0; k < BK; ++k) {
            float4 av = *(const float4*)&As[k][ty * 4];
            float4 wv = *(const float4*)&Ws[k][tx * 4];
            #pragma unroll
            for (int rr = 0; rr < 4; ++rr) {
                float ar = (&av.x)[rr];
                acc[rr][0] = fmaf(ar, wv.x, acc[rr][0]);
                acc[rr][1] = fmaf(ar, wv.y, acc[rr][1]);
                acc[rr][2] = fmaf(ar, wv.z, acc[rr][2]);
                acc[rr][3] = fmaf(ar, wv.w, acc[rr][3]);
            }
        }
        __syncthreads();
    }

    #pragma unroll
    for (int rr = 0; rr < 4; ++rr) {
        int row = m0 + ty * 4 + rr;
        #pragma unroll
        for (int cc = 0; cc < 4; ++cc) {
            int col = n0 + tx * 4 + cc;
            float v = acc[rr][cc];
            if (EPI == 3) {
                v += bias[row];
                v = fmaxf(v, 0.f) + log1pf(__expf(-fabsf(v)));
            }
            C[(size_t)row * N + col] = v;
        }
    }
}

// -------------------- causal conv (K=4) + bias + silu, bf16 in/out ------
// 64t x 64i tile. Writes xsb[tok][i] (bf16, x_proj input) + channel-major
// xs_T[i][tok], gate_T[i][tok] (bf16, silu pre-applied) via LDS transpose.
__global__ __launch_bounds__(256) void conv_silu_kernel(const u16* __restrict__ proj,
                                                        const float* __restrict__ cw,
                                                        const float* __restrict__ cb,
                                                        u16* __restrict__ xsb,
                                                        u16* __restrict__ xs_T,
                                                        u16* __restrict__ gate_T) {
    __shared__ float tX[64][65];
    __shared__ float tG[64][65];
    int bidx = blockIdx.x;              // b*128 + tt*8 + it
    int b  = bidx >> 7;
    int tt = (bidx >> 3) & 15;
    int it = bidx & 7;
    int t0 = tt * 64, i0 = it * 64;
    int tr = threadIdx.x >> 6, ii = threadIdx.x & 63;
    int i = i0 + ii;
    float w0 = cw[i * 4 + 0], w1 = cw[i * 4 + 1], w2 = cw[i * 4 + 2], w3 = cw[i * 4 + 3];
    float bias = cb[i];

    #pragma unroll 4
    for (int r = 0; r < 16; ++r) {
        int tl = tr * 16 + r;
        int t = t0 + tl;
        const u16* p = proj + ((size_t)(b * LSEQ + t)) * (2 * IDIM) + i;
        float acc = bias;
        acc = fmaf((t >= 3 ? bf2f(p[-3 * 2 * IDIM]) : 0.f), w0, acc);
        acc = fmaf((t >= 2 ? bf2f(p[-2 * 2 * IDIM]) : 0.f), w1, acc);
        acc = fmaf((t >= 1 ? bf2f(p[-1 * 2 * IDIM]) : 0.f), w2, acc);
        acc = fmaf(bf2f(p[0]), w3, acc);
        float xsv = acc / (1.f + __expf(-acc));
        xsb[(size_t)(b * LSEQ + t) * IDIM + i] = f2bf(xsv);
        tX[tl][ii] = xsv;
        float g = bf2f(p[IDIM]);
        tG[tl][ii] = g / (1.f + __expf(-g));
    }
    __syncthreads();
    #pragma unroll 4
    for (int r = 0; r < 16; ++r) {
        int il = tr * 16 + r;
        size_t off = (size_t)(i0 + il) * TOK + b * LSEQ + t0 + ii;
        xs_T[off]   = f2bf(tX[ii][il]);
        gate_T[off] = f2bf(tG[ii][il]);
    }
}

// -------------------- SSM scan: chunked two-pass, all-stream operands --------
__global__ __launch_bounds__(256) void scan_kernel(const float* __restrict__ dt_T,
                                                   const u16* __restrict__ xs_T,
                                                   const u16* __restrict__ gate_T,
                                                   const float* __restrict__ Bt,
                                                   const float* __restrict__ Ct,
                                                   const float* __restrict__ A_log,
                                                   const float* __restrict__ Dw,
                                                   u16* __restrict__ yb) {
    const int NC = 16;
    int n = threadIdx.x & 15;
    int c = threadIdx.x >> 4;

    int lin = (blockIdx.x & 7) * 256 + (blockIdx.x >> 3);   // XCD swizzle
    int b = lin >> 9;
    int i = lin & (IDIM - 1);

    float A = -__expf(A_log[i * NST + n]);

    __shared__ float aprodS[NC][17];
    __shared__ float stendS[NC][17];
    __shared__ float incS[NC][17];

    int t0 = c * 64;
    size_t coff = (size_t)i * TOK + b * LSEQ + t0;
    size_t noff = (size_t)(b * 16 + n) * LSEQ + t0;
    const float4* dtp = (const float4*)(dt_T + coff);
    const uint2*  xsp = (const uint2*)(xs_T + coff);
    const uint2*  gp  = (const uint2*)(gate_T + coff);
    const float4* Bp  = (const float4*)(Bt + noff);
    const float4* Cp  = (const float4*)(Ct + noff);

    // ---- phase 1 ----
    float aprod = 1.f, st = 0.f;
    for (int q = 0; q < 16; ++q) {
        float4 d4 = dtp[q];
        uint2  xu = xsp[q];
        float4 B4 = Bp[q];
        #pragma unroll
        for (int j = 0; j < 4; ++j) {
            float dtv = (&d4.x)[j];
            float dA  = __expf(dtv * A);
            aprod *= dA;
            st = fmaf(dA, st, dtv * bfup(xu, j) * (&B4.x)[j]);
        }
    }
    aprodS[c][n] = aprod;
    stendS[c][n] = st;
    __syncthreads();

    // ---- phase 2 ----
    if (threadIdx.x < 16) {
        int nn = threadIdx.x;
        float carry = 0.f;
        for (int cc = 0; cc < NC; ++cc) {
            incS[cc][nn] = carry;
            carry = fmaf(aprodS[cc][nn], carry, stendS[cc][nn]);
        }
    }
    __syncthreads();

    // ---- phase 3 ----
    st = incS[c][n];
    float Dv = Dw[i];
    u16* y_b = yb + ((size_t)b * LSEQ + t0) * IDIM + i;

    for (int q = 0; q < 16; ++q) {
        float4 d4 = dtp[q];
        uint2  xu = xsp[q];
        uint2  gu = gp[q];
        float4 B4 = Bp[q];
        float4 C4 = Cp[q];
        #pragma unroll
        for (int j = 0; j < 4; ++j) {
            float dtv = (&d4.x)[j];
            float xv  = bfup(xu, j);
            float dA  = __expf(dtv * A);
            st = fmaf(dA, st, dtv * xv * (&B4.x)[j]);
            float py = st * (&C4.x)[j];
            DPP_ROW_ADD(py, 0xB1);   // xor 1
            DPP_ROW_ADD(py, 0x4E);   // xor 2
            DPP_ROW_ADD(py, 0x141);  // ^7
            DPP_ROW_ADD(py, 0x140);  // ^15
            if (n == 0) {
                float yv = (py + xv * Dv) * bfup(gu, j);
                y_b[(size_t)(q * 4 + j) * IDIM] = f2bf(yv);
            }
        }
    }
}

// -------------------- final norm (pooled rows only) + MLP head --------------------
__global__ __launch_bounds__(256) void head_kernel(const float* __restrict__ h,
                                                   const int* __restrict__ lengths,
                                                   const float* __restrict__ fw,
                                                   const float* __restrict__ w1,
                                                   const float* __restrict__ b1,
                                                   const float* __restrict__ w2,
                                                   const float* __restrict__ b2,
                                                   float* __restrict__ out) {
    int b = blockIdx.x;
    int c = threadIdx.x;
    int len = lengths[b];
    const float* row = h + ((size_t)b * LSEQ + (len - 1)) * HDIM;
    float v = row[c];
    float s = v * v;
    #pragma unroll
    for (int m = 32; m >= 1; m >>= 1) s += __shfl_xor(s, m, 64);
    __shared__ float ls[4];
    __shared__ float pooled[HDIM];
    __shared__ float hd[64];
    if ((c & 63) == 0) ls[c >> 6] = s;
    __syncthreads();
    float tot = ls[0] + ls[1] + ls[2] + ls[3];
    float rstd = rsqrtf(tot * (1.0f / HDIM) + 1e-5f);
    pooled[c] = v * rstd * fw[c];
    __syncthreads();
    if (c < 64) {
        float a = b1[c];
        for (int k = 0; k < HDIM; ++k) a = fmaf(pooled[k], w1[c * HDIM + k], a);
        float g = 0.5f * a * (1.f + erff(a * 0.70710678118654752f));
        hd[c] = g * w2[c];
    }
    __syncthreads();
    if (c == 0) {
        float o = b2[0];
        for (int k = 0; k < 64; ++k) o += hd[k];
        out[b] = o;
    }
}

extern "C" void kernel_launch(void* const* d_in, const int* in_sizes, int n_in,
                              void* d_out, int out_size, void* d_ws, size_t ws_size,
                              hipStream_t stream) {
    const int*   ids         = (const int*)d_in[0];
    const int*   lengths     = (const int*)d_in[1];
    const float* embed       = (const float*)d_in[2];
    const float* norm_w      = (const float*)d_in[3];
    const float* in_proj_w   = (const float*)d_in[4];
    const float* conv_w      = (const float*)d_in[5];
    const float* conv_b      = (const float*)d_in[6];
    const float* x_proj_w    = (const float*)d_in[7];
    const float* dt_proj_w   = (const float*)d_in[8];
    const float* dt_proj_b   = (const float*)d_in[9];
    const float* A_log       = (const float*)d_in[10];
    const float* Dw          = (const float*)d_in[11];
    const float* out_proj_w  = (const float*)d_in[12];
    const float* final_norm_w= (const float*)d_in[13];
    const float* head_w1     = (const float*)d_in[14];
    const float* head_b1     = (const float*)d_in[15];
    const float* head_w2     = (const float*)d_in[16];
    const float* head_b2     = (const float*)d_in[17];

    float* ws   = (float*)d_ws;
    float* h    = ws;                        // 1,048,576 f32
    float* dtT  = h    + 1048576;            // 2,097,152 f32 (dt_T [512][4096])
    float* dtr  = dtT  + 2097152;            //    65,536 f32 ([4096][16])
    float* Bt   = dtr  + 65536;              //    65,536 f32 ([64][1024])
    float* Ct   = Bt   + 65536;              //    65,536 f32
    u16* xb   = (u16*)(Ct + 65536);          // 1,048,576 bf16
    u16* yb   = xb   + 1048576;              // 2,097,152 bf16
    u16* wib  = yb   + 2097152;              // 1,048,576 bf16 (in_proj_w)
    u16* wob  = wib  + 1048576;              //   524,288 bf16 (out_proj_w)
    u16* xwb  = wob  + 524288;               //    98,304 bf16 (x_proj_w)
    u16* projb= xwb  + 98304;                // 4,194,304 bf16 ([tok][1024])
    u16* xsb  = projb+ 4194304;              // 2,097,152 bf16 ([tok][512])
    u16* xsT  = xsb  + 2097152;              // 2,097,152 bf16 ([i][tok])
    u16* gT   = xsT  + 2097152;              // 2,097,152 bf16 ([i][tok])

    embed_kernel<<<TOK * HDIM / 256, 256, 0, stream>>>(ids, embed, h);
    cvt_bf16_kernel<<<1048576 / 4 / 256, 256, 0, stream>>>(in_proj_w, wib, 1048576);
    cvt_bf16_kernel<<<524288 / 4 / 256, 256, 0, stream>>>(out_proj_w, wob, 524288);
    cvt_bf16_kernel<<<98304 / 4 / 256, 256, 0, stream>>>(x_proj_w, xwb, 98304);

    for (int l = 0; l < LAYERS; ++l) {
        rmsnorm_kernel<<<TOK, 256, 0, stream>>>(h, norm_w + l * HDIM, xb);
        gemm_bf16_kernel<2><<<dim3(1024 / 128, TOK / 128), 256, 0, stream>>>(
            xb, wib + (size_t)l * 2 * IDIM * HDIM, (float*)projb, TOK, 2 * IDIM, HDIM);
        conv_silu_kernel<<<512, 256, 0, stream>>>(
            projb, conv_w + l * IDIM * KCONV, conv_b + l * IDIM, xsb, xsT, gT);
        xproj_kernel<<<TOK / 64, 256, 0, stream>>>(
            xsb, xwb + (size_t)l * 48 * IDIM, dtr, Bt, Ct);
        // dt_T[i][tok] = softplus(dt_w @ dtr^T + b[i]): A=dt_proj_w [512][16], W=dtr [4096][16]
        gemm_kernel<3><<<dim3(TOK / 64, IDIM / 64), 256, 0, stream>>>(
            dt_proj_w + (size_t)l * IDIM * 16, dtr, dt_proj_b + l * IDIM, dtT,
            IDIM, TOK, 16, 16, 16);
        scan_kernel<<<BATCH * IDIM, 256, 0, stream>>>(
            dtT, xsT, gT, Bt, Ct, A_log + (size_t)l * IDIM * NST, Dw + l * IDIM, yb);
        gemm_bf16_kernel<1><<<dim3(HDIM / 128, TOK / 128), 256, 0, stream>>>(
            yb, wob + (size_t)l * HDIM * IDIM, h, TOK, HDIM, IDIM);
    }

    head_kernel<<<BATCH, 256, 0, stream>>>(h, lengths, final_norm_w,
                                           head_w1, head_b1, head_w2, head_b2,
                                           (float*)d_out);
}

// Round 8
// 495.050 us; speedup vs baseline: 1.4157x; 1.4157x over previous
//
#include <hip/hip_runtime.h>
#include <hip/hip_bf16.h>

#define HDIM 256
#define IDIM 512
#define NST 16
#define KCONV 4
#define LAYERS 4
#define BATCH 4
#define LSEQ 1024
#define TOK (BATCH * LSEQ)   // 4096

typedef unsigned short u16;
typedef float f32x4 __attribute__((ext_vector_type(4)));
typedef short bf16x8 __attribute__((ext_vector_type(8)));

static __device__ __forceinline__ u16 f2bf(float f) {
    __hip_bfloat16 h = __float2bfloat16(f);
    return reinterpret_cast<u16&>(h);
}
static __device__ __forceinline__ float bf2f(u16 b) {
    return __builtin_bit_cast(float, (unsigned)b << 16);
}
// unpack bf16 #j (j=0..3) from a uint2 holding 4 packed bf16
static __device__ __forceinline__ float bfup(uint2 u, int j) {
    unsigned w = (j < 2) ? u.x : u.y;
    unsigned bits = (j & 1) ? (w & 0xffff0000u) : (w << 16);
    return __builtin_bit_cast(float, bits);
}

// DPP butterfly add over each 16-lane row (all lanes end with the row sum).
#define DPP_ROW_ADD(p, CTRL)                                                   \
    p += __builtin_bit_cast(float, __builtin_amdgcn_update_dpp(                \
             0, __builtin_bit_cast(int, p), CTRL, 0xf, 0xf, false))

// -------------------- embedding --------------------
__global__ __launch_bounds__(256) void embed_kernel(const int* __restrict__ ids,
                                                    const float* __restrict__ embed,
                                                    float* __restrict__ h) {
    int idx = blockIdx.x * 256 + threadIdx.x;
    if (idx < TOK * HDIM) {
        int tok = idx >> 8;
        int c = idx & (HDIM - 1);
        h[idx] = embed[ids[tok] * HDIM + c];
    }
}

// -------------------- f32 -> bf16 bulk convert (weights) --------------------
__global__ __launch_bounds__(256) void cvt_bf16_kernel(const float* __restrict__ in,
                                                       u16* __restrict__ out, int n) {
    int j = (blockIdx.x * 256 + threadIdx.x) * 4;
    if (j < n) {
        float4 v = *(const float4*)&in[j];
        unsigned lo = (unsigned)f2bf(v.x) | ((unsigned)f2bf(v.y) << 16);
        unsigned hi = (unsigned)f2bf(v.z) | ((unsigned)f2bf(v.w) << 16);
        *(uint2*)&out[j] = make_uint2(lo, hi);
    }
}

// -------------------- rmsnorm (per token row of H=256), bf16 out --------------------
__global__ __launch_bounds__(256) void rmsnorm_kernel(const float* __restrict__ h,
                                                      const float* __restrict__ w,
                                                      u16* __restrict__ xb) {
    int tok = blockIdx.x;
    int c = threadIdx.x;
    float v = h[tok * HDIM + c];
    float s = v * v;
    #pragma unroll
    for (int m = 32; m >= 1; m >>= 1) s += __shfl_xor(s, m, 64);
    __shared__ float ls[4];
    __shared__ float rstd_s;
    int wid = threadIdx.x >> 6;
    if ((threadIdx.x & 63) == 0) ls[wid] = s;
    __syncthreads();
    if (threadIdx.x == 0) {
        float tot = ls[0] + ls[1] + ls[2] + ls[3];
        rstd_s = rsqrtf(tot * (1.0f / HDIM) + 1e-5f);
    }
    __syncthreads();
    xb[tok * HDIM + c] = f2bf(v * rstd_s * w[c]);
}

// -------------------- bf16 MFMA GEMM: C[M,N] = A[M,K](bf16) @ W[N,K](bf16)^T ----
// EPI: 1 = accumulate f32 (residual), 2 = store bf16.
template <int EPI>
__global__ __launch_bounds__(256) void gemm_bf16_kernel(const u16* __restrict__ A,
                                                        const u16* __restrict__ W,
                                                        float* __restrict__ C,
                                                        int M, int N, int K) {
    const int BM = 128, BK = 32;
    __shared__ __align__(16) u16 Al[BM][BK + 8];
    __shared__ __align__(16) u16 Bl[BM][BK + 8];
    int m0 = blockIdx.y * BM, n0 = blockIdx.x * BM;
    int tid = threadIdx.x;
    int lane = tid & 63;
    int wid = tid >> 6;
    int wr = wid >> 1, wc = wid & 1;
    int r = lane & 15, g = lane >> 4;

    f32x4 acc[4][4] = {};

    int srow = tid & 127;
    const u16* src = (tid < 128) ? (A + (size_t)(m0 + srow) * K)
                                 : (W + (size_t)(n0 + srow) * K);
    u16* dstrow = (tid < 128) ? &Al[srow][0] : &Bl[srow][0];

    for (int k0 = 0; k0 < K; k0 += BK) {
        uint4 v0 = *(const uint4*)(src + k0);
        uint4 v1 = *(const uint4*)(src + k0 + 8);
        uint4 v2 = *(const uint4*)(src + k0 + 16);
        uint4 v3 = *(const uint4*)(src + k0 + 24);
        __syncthreads();
        *(uint4*)(dstrow)      = v0;
        *(uint4*)(dstrow + 8)  = v1;
        *(uint4*)(dstrow + 16) = v2;
        *(uint4*)(dstrow + 24) = v3;
        __syncthreads();

        bf16x8 af[4], bfr[4];
        #pragma unroll
        for (int f = 0; f < 4; ++f) {
            af[f]  = *(const bf16x8*)&Al[wr * 64 + f * 16 + r][g * 8];
            bfr[f] = *(const bf16x8*)&Bl[wc * 64 + f * 16 + r][g * 8];
        }
        #pragma unroll
        for (int fm = 0; fm < 4; ++fm)
            #pragma unroll
            for (int fn = 0; fn < 4; ++fn)
                acc[fm][fn] = __builtin_amdgcn_mfma_f32_16x16x32_bf16(
                    af[fm], bfr[fn], acc[fm][fn], 0, 0, 0);
    }

    #pragma unroll
    for (int fm = 0; fm < 4; ++fm) {
        #pragma unroll
        for (int fn = 0; fn < 4; ++fn) {
            int col = n0 + wc * 64 + fn * 16 + r;
            #pragma unroll
            for (int v = 0; v < 4; ++v) {
                int row = m0 + wr * 64 + fm * 16 + g * 4 + v;
                if (EPI == 1) C[(size_t)row * N + col] += acc[fm][fn][v];
                else          ((u16*)C)[(size_t)row * N + col] = f2bf(acc[fm][fn][v]);
            }
        }
    }
}

// -------------------- x_proj fused: xs-tile -> dtr + bc (B,C token-major) --------
// One block = 64 tokens. bf16 MFMA over K=512: out[64][48], then epilogue writes
// dtr[tok][16] (f32) and bc[(b*1024+t)*32 + {n | 16+n}] = {B, C} (f32).
__global__ __launch_bounds__(256) void xproj_kernel(const u16* __restrict__ A,   // xsb [TOK][512]
                                                    const u16* __restrict__ W,   // xwb [48][512]
                                                    float* __restrict__ dtr,
                                                    float* __restrict__ bc) {
    const int BK = 32;
    __shared__ __align__(16) u16 Al[64][BK + 8];
    __shared__ __align__(16) u16 Bl[48][BK + 8];
    __shared__ float sT[64][52];
    int m0 = blockIdx.x * 64;
    int tid = threadIdx.x;
    int lane = tid & 63;
    int wid = tid >> 6;
    int r = lane & 15, g = lane >> 4;

    f32x4 acc[3] = {};

    const u16* src = nullptr;
    u16* dstrow = nullptr;
    if (tid < 64)       { src = A + (size_t)(m0 + tid) * 512; dstrow = &Al[tid][0]; }
    else if (tid < 112) { src = W + (size_t)(tid - 64) * 512; dstrow = &Bl[tid - 64][0]; }

    for (int k0 = 0; k0 < 512; k0 += BK) {
        uint4 v0, v1, v2, v3;
        if (tid < 112) {
            v0 = *(const uint4*)(src + k0);
            v1 = *(const uint4*)(src + k0 + 8);
            v2 = *(const uint4*)(src + k0 + 16);
            v3 = *(const uint4*)(src + k0 + 24);
        }
        __syncthreads();
        if (tid < 112) {
            *(uint4*)(dstrow)      = v0;
            *(uint4*)(dstrow + 8)  = v1;
            *(uint4*)(dstrow + 16) = v2;
            *(uint4*)(dstrow + 24) = v3;
        }
        __syncthreads();

        bf16x8 af = *(const bf16x8*)&Al[wid * 16 + r][g * 8];
        #pragma unroll
        for (int fn = 0; fn < 3; ++fn) {
            bf16x8 bfr = *(const bf16x8*)&Bl[fn * 16 + r][g * 8];
            acc[fn] = __builtin_amdgcn_mfma_f32_16x16x32_bf16(af, bfr, acc[fn], 0, 0, 0);
        }
    }

    #pragma unroll
    for (int fn = 0; fn < 3; ++fn) {
        int col = fn * 16 + r;
        #pragma unroll
        for (int v = 0; v < 4; ++v)
            sT[wid * 16 + g * 4 + v][col] = acc[fn][v];
    }
    __syncthreads();

    int b  = m0 >> 10;
    int tl = m0 & 1023;
    if (tid < 64) {
        float4* dst = (float4*)&dtr[(size_t)(m0 + tid) * 16];
        const float4* s4 = (const float4*)&sT[tid][0];
        dst[0] = s4[0]; dst[1] = s4[1]; dst[2] = s4[2]; dst[3] = s4[3];
    }
    // bc: token-major so scan lanes n=0..15 read consecutive floats (1 line / 16 lanes)
    #pragma unroll
    for (int k = 0; k < 4; ++k) {
        int idx = tid + k * 256;        // 0..1023 = 64t x 16n
        int t = idx >> 4, n = idx & 15;
        size_t off = (size_t)(b * LSEQ + tl + t) * 32;
        bc[off + n]      = sT[t][16 + n];
        bc[off + 16 + n] = sT[t][32 + n];
    }
}

// -------------------- generic f32 tiled GEMM (dt projection) --------------------
// C[M,N] = A[M,K(lda)] @ W[N,K(ldw)]^T; EPI 3 = softplus(acc + bias[row])
template <int EPI>
__global__ __launch_bounds__(256) void gemm_kernel(const float* __restrict__ A,
                                                   const float* __restrict__ W,
                                                   const float* __restrict__ bias,
                                                   float* __restrict__ C,
                                                   int M, int N, int K, int lda, int ldw) {
    const int BM = 64, BN = 64, BK = 16;
    __shared__ float As[BK][BM];
    __shared__ float Ws[BK][BN];
    int m0 = blockIdx.y * BM, n0 = blockIdx.x * BN;
    int tid = threadIdx.x;
    int tx = tid & 15, ty = tid >> 4;
    int lm = tid >> 2, lk = (tid & 3) * 4;

    float acc[4][4] = {};

    for (int k0 = 0; k0 < K; k0 += BK) {
        float4 a4 = *(const float4*)&A[(size_t)(m0 + lm) * lda + k0 + lk];
        As[lk + 0][lm] = a4.x; As[lk + 1][lm] = a4.y;
        As[lk + 2][lm] = a4.z; As[lk + 3][lm] = a4.w;
        float4 w4 = *(const float4*)&W[(size_t)(n0 + lm) * ldw + k0 + lk];
        Ws[lk + 0][lm] = w4.x; Ws[lk + 1][lm] = w4.y;
        Ws[lk + 2][lm] = w4.z; Ws[lk + 3][lm] = w4.w;
        __syncthreads();
        #pragma unroll
        for (int k = 0; k < BK; ++k) {
            float4 av = *(const float4*)&As[k][ty * 4];
            float4 wv = *(const float4*)&Ws[k][tx * 4];
            #pragma unroll
            for (int rr = 0; rr < 4; ++rr) {
                float ar = (&av.x)[rr];
                acc[rr][0] = fmaf(ar, wv.x, acc[rr][0]);
                acc[rr][1] = fmaf(ar, wv.y, acc[rr][1]);
                acc[rr][2] = fmaf(ar, wv.z, acc[rr][2]);
                acc[rr][3] = fmaf(ar, wv.w, acc[rr][3]);
            }
        }
        __syncthreads();
    }

    #pragma unroll
    for (int rr = 0; rr < 4; ++rr) {
        int row = m0 + ty * 4 + rr;
        #pragma unroll
        for (int cc = 0; cc < 4; ++cc) {
            int col = n0 + tx * 4 + cc;
            float v = acc[rr][cc];
            if (EPI == 3) {
                v += bias[row];
                v = fmaxf(v, 0.f) + log1pf(__expf(-fabsf(v)));
            }
            C[(size_t)row * N + col] = v;
        }
    }
}

// -------------------- causal conv (K=4) + bias + silu, bf16 in/out ------
__global__ __launch_bounds__(256) void conv_silu_kernel(const u16* __restrict__ proj,
                                                        const float* __restrict__ cw,
                                                        const float* __restrict__ cb,
                                                        u16* __restrict__ xsb,
                                                        u16* __restrict__ xs_T,
                                                        u16* __restrict__ gate_T) {
    __shared__ float tX[64][65];
    __shared__ float tG[64][65];
    int bidx = blockIdx.x;              // b*128 + tt*8 + it
    int b  = bidx >> 7;
    int tt = (bidx >> 3) & 15;
    int it = bidx & 7;
    int t0 = tt * 64, i0 = it * 64;
    int tr = threadIdx.x >> 6, ii = threadIdx.x & 63;
    int i = i0 + ii;
    float w0 = cw[i * 4 + 0], w1 = cw[i * 4 + 1], w2 = cw[i * 4 + 2], w3 = cw[i * 4 + 3];
    float bias = cb[i];

    #pragma unroll 4
    for (int r = 0; r < 16; ++r) {
        int tl = tr * 16 + r;
        int t = t0 + tl;
        const u16* p = proj + ((size_t)(b * LSEQ + t)) * (2 * IDIM) + i;
        float acc = bias;
        acc = fmaf((t >= 3 ? bf2f(p[-3 * 2 * IDIM]) : 0.f), w0, acc);
        acc = fmaf((t >= 2 ? bf2f(p[-2 * 2 * IDIM]) : 0.f), w1, acc);
        acc = fmaf((t >= 1 ? bf2f(p[-1 * 2 * IDIM]) : 0.f), w2, acc);
        acc = fmaf(bf2f(p[0]), w3, acc);
        float xsv = acc / (1.f + __expf(-acc));
        xsb[(size_t)(b * LSEQ + t) * IDIM + i] = f2bf(xsv);
        tX[tl][ii] = xsv;
        float g = bf2f(p[IDIM]);
        tG[tl][ii] = g / (1.f + __expf(-g));
    }
    __syncthreads();
    #pragma unroll 4
    for (int r = 0; r < 16; ++r) {
        int il = tr * 16 + r;
        size_t off = (size_t)(i0 + il) * TOK + b * LSEQ + t0 + ii;
        xs_T[off]   = f2bf(tX[ii][il]);
        gate_T[off] = f2bf(tG[ii][il]);
    }
}

// -------------------- SSM scan: chunked two-pass, stream dt/xs/g + coalesced B/C ----
__global__ __launch_bounds__(256) void scan_kernel(const float* __restrict__ dt_T,
                                                   const u16* __restrict__ xs_T,
                                                   const u16* __restrict__ gate_T,
                                                   const float* __restrict__ bc,
                                                   const float* __restrict__ A_log,
                                                   const float* __restrict__ Dw,
                                                   u16* __restrict__ yb) {
    const int NC = 16;
    int n = threadIdx.x & 15;
    int c = threadIdx.x >> 4;

    int lin = (blockIdx.x & 7) * 256 + (blockIdx.x >> 3);   // XCD swizzle
    int b = lin >> 9;
    int i = lin & (IDIM - 1);

    float A = -__expf(A_log[i * NST + n]);

    __shared__ float aprodS[NC][17];
    __shared__ float stendS[NC][17];
    __shared__ float incS[NC][17];

    int t0 = c * 64;
    size_t coff = (size_t)i * TOK + b * LSEQ + t0;
    const float4* dtp = (const float4*)(dt_T + coff);
    const uint2*  xsp = (const uint2*)(xs_T + coff);
    const uint2*  gp  = (const uint2*)(gate_T + coff);
    const float*  sb  = bc + ((size_t)b * LSEQ + t0) * 32 + n;   // B at +0, C at +16

    // ---- phase 1 ----
    float aprod = 1.f, st = 0.f;
    for (int q = 0; q < 16; ++q) {
        float4 d4 = dtp[q];
        uint2  xu = xsp[q];
        const float* sq = sb + q * 128;
        #pragma unroll
        for (int j = 0; j < 4; ++j) {
            float dtv = (&d4.x)[j];
            float dA  = __expf(dtv * A);
            aprod *= dA;
            st = fmaf(dA, st, dtv * bfup(xu, j) * sq[j * 32]);
        }
    }
    aprodS[c][n] = aprod;
    stendS[c][n] = st;
    __syncthreads();

    // ---- phase 2 ----
    if (threadIdx.x < 16) {
        int nn = threadIdx.x;
        float carry = 0.f;
        for (int cc = 0; cc < NC; ++cc) {
            incS[cc][nn] = carry;
            carry = fmaf(aprodS[cc][nn], carry, stendS[cc][nn]);
        }
    }
    __syncthreads();

    // ---- phase 3 ----
    st = incS[c][n];
    float Dv = Dw[i];
    u16* y_b = yb + ((size_t)b * LSEQ + t0) * IDIM + i;

    for (int q = 0; q < 16; ++q) {
        float4 d4 = dtp[q];
        uint2  xu = xsp[q];
        uint2  gu = gp[q];
        const float* sq = sb + q * 128;
        #pragma unroll
        for (int j = 0; j < 4; ++j) {
            float dtv = (&d4.x)[j];
            float xv  = bfup(xu, j);
            float dA  = __expf(dtv * A);
            st = fmaf(dA, st, dtv * xv * sq[j * 32]);
            float py = st * sq[j * 32 + 16];
            DPP_ROW_ADD(py, 0xB1);   // xor 1
            DPP_ROW_ADD(py, 0x4E);   // xor 2
            DPP_ROW_ADD(py, 0x141);  // ^7
            DPP_ROW_ADD(py, 0x140);  // ^15
            if (n == 0) {
                float yv = (py + xv * Dv) * bfup(gu, j);
                y_b[(size_t)(q * 4 + j) * IDIM] = f2bf(yv);
            }
        }
    }
}

// -------------------- final norm (pooled rows only) + MLP head --------------------
__global__ __launch_bounds__(256) void head_kernel(const float* __restrict__ h,
                                                   const int* __restrict__ lengths,
                                                   const float* __restrict__ fw,
                                                   const float* __restrict__ w1,
                                                   const float* __restrict__ b1,
                                                   const float* __restrict__ w2,
                                                   const float* __restrict__ b2,
                                                   float* __restrict__ out) {
    int b = blockIdx.x;
    int c = threadIdx.x;
    int len = lengths[b];
    const float* row = h + ((size_t)b * LSEQ + (len - 1)) * HDIM;
    float v = row[c];
    float s = v * v;
    #pragma unroll
    for (int m = 32; m >= 1; m >>= 1) s += __shfl_xor(s, m, 64);
    __shared__ float ls[4];
    __shared__ float pooled[HDIM];
    __shared__ float hd[64];
    if ((c & 63) == 0) ls[c >> 6] = s;
    __syncthreads();
    float tot = ls[0] + ls[1] + ls[2] + ls[3];
    float rstd = rsqrtf(tot * (1.0f / HDIM) + 1e-5f);
    pooled[c] = v * rstd * fw[c];
    __syncthreads();
    if (c < 64) {
        float a = b1[c];
        for (int k = 0; k < HDIM; ++k) a = fmaf(pooled[k], w1[c * HDIM + k], a);
        float g = 0.5f * a * (1.f + erff(a * 0.70710678118654752f));
        hd[c] = g * w2[c];
    }
    __syncthreads();
    if (c == 0) {
        float o = b2[0];
        for (int k = 0; k < 64; ++k) o += hd[k];
        out[b] = o;
    }
}

extern "C" void kernel_launch(void* const* d_in, const int* in_sizes, int n_in,
                              void* d_out, int out_size, void* d_ws, size_t ws_size,
                              hipStream_t stream) {
    const int*   ids         = (const int*)d_in[0];
    const int*   lengths     = (const int*)d_in[1];
    const float* embed       = (const float*)d_in[2];
    const float* norm_w      = (const float*)d_in[3];
    const float* in_proj_w   = (const float*)d_in[4];
    const float* conv_w      = (const float*)d_in[5];
    const float* conv_b      = (const float*)d_in[6];
    const float* x_proj_w    = (const float*)d_in[7];
    const float* dt_proj_w   = (const float*)d_in[8];
    const float* dt_proj_b   = (const float*)d_in[9];
    const float* A_log       = (const float*)d_in[10];
    const float* Dw          = (const float*)d_in[11];
    const float* out_proj_w  = (const float*)d_in[12];
    const float* final_norm_w= (const float*)d_in[13];
    const float* head_w1     = (const float*)d_in[14];
    const float* head_b1     = (const float*)d_in[15];
    const float* head_w2     = (const float*)d_in[16];
    const float* head_b2     = (const float*)d_in[17];

    float* ws   = (float*)d_ws;
    float* h    = ws;                        // 1,048,576 f32
    float* dtT  = h    + 1048576;            // 2,097,152 f32 (dt_T [512][4096])
    float* dtr  = dtT  + 2097152;            //    65,536 f32 ([4096][16])
    float* bc   = dtr  + 65536;              //   131,072 f32 ([4096][32]: B|C)
    u16* xb   = (u16*)(bc + 131072);         // 1,048,576 bf16
    u16* yb   = xb   + 1048576;              // 2,097,152 bf16
    u16* wib  = yb   + 2097152;              // 1,048,576 bf16 (in_proj_w)
    u16* wob  = wib  + 1048576;              //   524,288 bf16 (out_proj_w)
    u16* xwb  = wob  + 524288;               //    98,304 bf16 (x_proj_w)
    u16* projb= xwb  + 98304;                // 4,194,304 bf16 ([tok][1024])
    u16* xsb  = projb+ 4194304;              // 2,097,152 bf16 ([tok][512])
    u16* xsT  = xsb  + 2097152;              // 2,097,152 bf16 ([i][tok])
    u16* gT   = xsT  + 2097152;              // 2,097,152 bf16 ([i][tok])

    embed_kernel<<<TOK * HDIM / 256, 256, 0, stream>>>(ids, embed, h);
    cvt_bf16_kernel<<<1048576 / 4 / 256, 256, 0, stream>>>(in_proj_w, wib, 1048576);
    cvt_bf16_kernel<<<524288 / 4 / 256, 256, 0, stream>>>(out_proj_w, wob, 524288);
    cvt_bf16_kernel<<<98304 / 4 / 256, 256, 0, stream>>>(x_proj_w, xwb, 98304);

    for (int l = 0; l < LAYERS; ++l) {
        rmsnorm_kernel<<<TOK, 256, 0, stream>>>(h, norm_w + l * HDIM, xb);
        gemm_bf16_kernel<2><<<dim3(1024 / 128, TOK / 128), 256, 0, stream>>>(
            xb, wib + (size_t)l * 2 * IDIM * HDIM, (float*)projb, TOK, 2 * IDIM, HDIM);
        conv_silu_kernel<<<512, 256, 0, stream>>>(
            projb, conv_w + l * IDIM * KCONV, conv_b + l * IDIM, xsb, xsT, gT);
        xproj_kernel<<<TOK / 64, 256, 0, stream>>>(
            xsb, xwb + (size_t)l * 48 * IDIM, dtr, bc);
        // dt_T[i][tok] = softplus(dt_w @ dtr^T + b[i]): A=dt_proj_w [512][16], W=dtr [4096][16]
        gemm_kernel<3><<<dim3(TOK / 64, IDIM / 64), 256, 0, stream>>>(
            dt_proj_w + (size_t)l * IDIM * 16, dtr, dt_proj_b + l * IDIM, dtT,
            IDIM, TOK, 16, 16, 16);
        scan_kernel<<<BATCH * IDIM, 256, 0, stream>>>(
            dtT, xsT, gT, bc, A_log + (size_t)l * IDIM * NST, Dw + l * IDIM, yb);
        gemm_bf16_kernel<1><<<dim3(HDIM / 128, TOK / 128), 256, 0, stream>>>(
            yb, wob + (size_t)l * HDIM * IDIM, h, TOK, HDIM, IDIM);
    }

    head_kernel<<<BATCH, 256, 0, stream>>>(h, lengths, final_norm_w,
                                           head_w1, head_b1, head_w2, head_b2,
                                           (float*)d_out);
}